// Round 5
// baseline (541.466 us; speedup 1.0000x reference)
//
#include <hip/hip_runtime.h>

#define BATCH   8
#define CDIM    96
#define LSEQ    4096
#define DIN     192
#define DTR     6
#define DST     16
#define NCHUNK  64
#define CLEN    64
#define BL      (BATCH*LSEQ)

typedef unsigned short u16;
typedef unsigned int   u32;

__device__ __forceinline__ float b2f(u16 u) {
    union { u32 i; float f; } v; v.i = ((u32)u) << 16; return v.f;
}
__device__ __forceinline__ u16 f2b(float f) {
    union { float f; u32 i; } v; v.f = f;
    u32 x = v.i;
    return (u16)((x + 0x7fffu + ((x >> 16) & 1u)) >> 16);
}
__device__ __forceinline__ float silu_f(float x) { return x / (1.0f + expf(-x)); }
__device__ __forceinline__ float softplus_f(float x) {
    return fmaxf(x, 0.0f) + log1pf(expf(-fabsf(x)));
}
__device__ __forceinline__ void fma4(const float4 w, const float4 u, float& acc) {
    acc = fmaf(w.x, u.x, acc);
    acc = fmaf(w.y, u.y, acc);
    acc = fmaf(w.z, u.z, acc);
    acc = fmaf(w.w, u.w, acc);
}
// XOR-swizzled dword index within a tile of row-stride 96 dwords:
// 4-dword groups permuted by (row & 7) -> ds_read_b128 by lane=row is conflict-free.
__device__ __forceinline__ int swz(int row, int d) {
    return row * 96 + ((((d >> 2) ^ (row & 7)) << 2) | (d & 3));
}

// K1: stage x-tile -> in_proj x-half GEMM + z-half GEMM (wave-uniform scalar
// weights, lane=row) -> causal conv(4)+silu -> x_proj GEMM (fused old K2).
// grid (64, 8), block 256 (4 waves). LDS 50.3 KB.
__global__ __launch_bounds__(256) void k1_front(
    const float* __restrict__ x,    // (8,96,4096)
    const float* __restrict__ ipw,  // (384,96)
    const float* __restrict__ cvw,  // (192,4)
    const float* __restrict__ cvb,  // (192)
    const float* __restrict__ xpw,  // (38,192)
    u16* __restrict__ xc,           // (BL,192) silu(conv(xm)) bf16
    u16* __restrict__ zs,           // (BL,192) silu(z) bf16
    float* __restrict__ dtb,        // (BL,6)
    float* __restrict__ bcb)        // (BL,32) [B(16)|C(16)]
{
    __shared__ float uA[67 * 96];   // u fp32 swizzled; reused as xcs bf16 swizzled
    __shared__ u16  xmB[67 * 192];  // xm bf16, dword-swizzled
    const int b = blockIdx.y, l0 = blockIdx.x * 64, tid = threadIdx.x;
    const int wv = __builtin_amdgcn_readfirstlane(tid >> 6);
    const int lane = tid & 63;

    // ---- stage u (rows l0-3 .. l0+63), swizzled; coalesced global reads ----
    for (int idx = tid; idx < CDIM * 67; idx += 256) {
        int c = idx / 67, row = idx % 67, l = l0 + row - 3;
        float v = (l >= 0) ? x[((size_t)b * CDIM + c) * LSEQ + l] : 0.0f;
        uA[swz(row, c)] = v;
    }
    __syncthreads();

    u32* xmd = (u32*)xmB;
    // ---- in_proj x-half: wave wv owns col-groups wv*12..wv*12+11; lane=row ----
    {
        const int r7 = lane & 7;
        for (int g = 0; g < 12; ++g) {
            int col = (wv * 12 + g) * 4;
            const float4* w0 = (const float4*)(ipw + (size_t)(col + 0) * 96);
            const float4* w1 = (const float4*)(ipw + (size_t)(col + 1) * 96);
            const float4* w2 = (const float4*)(ipw + (size_t)(col + 2) * 96);
            const float4* w3 = (const float4*)(ipw + (size_t)(col + 3) * 96);
            float a0 = 0, a1 = 0, a2 = 0, a3 = 0;
            #pragma unroll
            for (int kk = 0; kk < 24; ++kk) {
                float4 u4 = *(const float4*)&uA[lane * 96 + ((kk ^ r7) << 2)];
                fma4(w0[kk], u4, a0);
                fma4(w1[kk], u4, a1);
                fma4(w2[kk], u4, a2);
                fma4(w3[kk], u4, a3);
            }
            int d0 = col >> 1;   // even, d0&3 in {0,2}
            int pi = lane * 96 + (((d0 >> 2) ^ r7) << 2) + (d0 & 3);
            xmd[pi]     = (u32)f2b(a0) | ((u32)f2b(a1) << 16);
            xmd[pi + 1] = (u32)f2b(a2) | ((u32)f2b(a3) << 16);
        }
    }
    // ---- in_proj z-half: rows 3..66 (lane+3) -> silu -> zs global ----
    {
        const int row = lane + 3, r7 = row & 7;
        for (int g = 0; g < 12; ++g) {
            int col = DIN + (wv * 12 + g) * 4;
            const float4* w0 = (const float4*)(ipw + (size_t)(col + 0) * 96);
            const float4* w1 = (const float4*)(ipw + (size_t)(col + 1) * 96);
            const float4* w2 = (const float4*)(ipw + (size_t)(col + 2) * 96);
            const float4* w3 = (const float4*)(ipw + (size_t)(col + 3) * 96);
            float a0 = 0, a1 = 0, a2 = 0, a3 = 0;
            #pragma unroll
            for (int kk = 0; kk < 24; ++kk) {
                float4 u4 = *(const float4*)&uA[row * 96 + ((kk ^ r7) << 2)];
                fma4(w0[kk], u4, a0);
                fma4(w1[kk], u4, a1);
                fma4(w2[kk], u4, a2);
                fma4(w3[kk], u4, a3);
            }
            u32 p0 = (u32)f2b(silu_f(a0)) | ((u32)f2b(silu_f(a1)) << 16);
            u32 p1 = (u32)f2b(silu_f(a2)) | ((u32)f2b(silu_f(a3)) << 16);
            *(uint2*)&zs[((size_t)b * LSEQ + l0 + lane) * DIN + (col - DIN)] =
                make_uint2(p0, p1);
        }
    }
    // ---- halo rows 64..66 of xm (per-lane cols; tiny) ----
    if (tid < 144) {
        int row = 64 + tid / 48, col = (tid % 48) * 4;
        const int r7 = row & 7;
        const float4* w0 = (const float4*)(ipw + (size_t)(col + 0) * 96);
        const float4* w1 = (const float4*)(ipw + (size_t)(col + 1) * 96);
        const float4* w2 = (const float4*)(ipw + (size_t)(col + 2) * 96);
        const float4* w3 = (const float4*)(ipw + (size_t)(col + 3) * 96);
        float a0 = 0, a1 = 0, a2 = 0, a3 = 0;
        for (int kk = 0; kk < 24; ++kk) {
            float4 u4 = *(const float4*)&uA[row * 96 + ((kk ^ r7) << 2)];
            fma4(w0[kk], u4, a0);
            fma4(w1[kk], u4, a1);
            fma4(w2[kk], u4, a2);
            fma4(w3[kk], u4, a3);
        }
        int d0 = col >> 1;
        int pi = row * 96 + (((d0 >> 2) ^ r7) << 2) + (d0 & 3);
        xmd[pi]     = (u32)f2b(a0) | ((u32)f2b(a1) << 16);
        xmd[pi + 1] = (u32)f2b(a2) | ((u32)f2b(a3) << 16);
    }
    __syncthreads();

    // ---- causal conv(4) + bias + silu -> xc global + xcs (reuse uA) ----
    u16* xcs = (u16*)uA;
    for (int idx = tid; idx < 64 * DIN; idx += 256) {
        int lr = idx / DIN, ch = idx % DIN;
        int d = ch >> 1, half = ch & 1;
        float acc = cvb[ch];
        #pragma unroll
        for (int k = 0; k < 4; ++k) {
            int row = lr + k;
            u32 pw = xmd[row * 96 + (((d >> 2) ^ (row & 7)) << 2) + (d & 3)];
            u16 hv = half ? (u16)(pw >> 16) : (u16)(pw & 0xffff);
            acc = fmaf(cvw[ch * 4 + k], b2f(hv), acc);
        }
        u16 rb = f2b(silu_f(acc));
        xc[((size_t)b * LSEQ + l0 + lr) * DIN + ch] = rb;
        xcs[(lr * 96 + (((d >> 2) ^ (lr & 7)) << 2) + (d & 3)) * 2 + half] = rb;
    }
    __syncthreads();

    // ---- x_proj: 38 cols, wave-strided; lane=row; K=192 bf16 from xcs ----
    {
        const int r7 = lane & 7;
        const u32* xd = (const u32*)uA;
        for (int c = wv; c < 38; c += 4) {
            const float4* wp = (const float4*)(xpw + (size_t)c * DIN);
            float acc = 0.0f;
            #pragma unroll
            for (int g = 0; g < 24; ++g) {
                uint4 q = *(const uint4*)&xd[lane * 96 + ((g ^ r7) << 2)];
                float4 wa = wp[g * 2], wb = wp[g * 2 + 1];
                acc = fmaf(b2f((u16)(q.x & 0xffff)), wa.x, acc);
                acc = fmaf(b2f((u16)(q.x >> 16)),    wa.y, acc);
                acc = fmaf(b2f((u16)(q.y & 0xffff)), wa.z, acc);
                acc = fmaf(b2f((u16)(q.y >> 16)),    wa.w, acc);
                acc = fmaf(b2f((u16)(q.z & 0xffff)), wb.x, acc);
                acc = fmaf(b2f((u16)(q.z >> 16)),    wb.y, acc);
                acc = fmaf(b2f((u16)(q.w & 0xffff)), wb.z, acc);
                acc = fmaf(b2f((u16)(q.w >> 16)),    wb.w, acc);
            }
            size_t row = (size_t)b * LSEQ + l0 + lane;
            if (c < DTR) dtb[row * DTR + c] = acc;
            else         bcb[row * 32 + (c - DTR)] = acc;
        }
    }
}

// K3 (pass A): chunk-local scan, xc tile staged in LDS. grid (64,8), block 192.
__global__ __launch_bounds__(192) void k3_scan_partial(
    const u16* __restrict__ xc,
    const float* __restrict__ dtbuf,
    const float* __restrict__ bcb,
    const float* __restrict__ dpw,   // (192,6)
    const float* __restrict__ dpb,   // (192)
    const float* __restrict__ alog,  // (192,16)
    float* __restrict__ ph)          // (B,NCHUNK,192,32) [P(16)|hend(16)]
{
    __shared__ float dts[CLEN * 6];
    __shared__ float bcs[CLEN * 32];
    __shared__ u16 xcs[CLEN * 192];
    const int b = blockIdx.y, s = blockIdx.x, e = threadIdx.x;
    const size_t rb = (size_t)b * LSEQ + s * CLEN;
    for (int i = e; i < CLEN * 6; i += 192)  dts[i] = dtbuf[rb * 6 + i];
    for (int i = e; i < CLEN * 32; i += 192) bcs[i] = bcb[rb * 32 + i];
    {
        const u32* src = (const u32*)(xc + rb * DIN);
        u32* dd = (u32*)xcs;
        for (int i = e; i < 6144; i += 192) dd[i] = src[i];
    }
    float wr[6];
    #pragma unroll
    for (int r = 0; r < 6; ++r) wr[r] = dpw[e * 6 + r];
    const float bias = dpb[e];
    float m[DST];
    #pragma unroll
    for (int n = 0; n < DST; ++n) m[n] = -expf(alog[e * DST + n]);
    float h[DST], P[DST];
    #pragma unroll
    for (int n = 0; n < DST; ++n) { h[n] = 0.0f; P[n] = 1.0f; }
    __syncthreads();
    for (int j = 0; j < CLEN; ++j) {
        float u = b2f(xcs[j * 192 + e]);
        float xdt = bias;
        #pragma unroll
        for (int r = 0; r < 6; ++r) xdt = fmaf(dts[j * 6 + r], wr[r], xdt);
        float delta = softplus_f(xdt);
        float du = delta * u;
        #pragma unroll
        for (int n = 0; n < DST; ++n) {
            float dA = expf(delta * m[n]);
            h[n] = fmaf(dA, h[n], du * bcs[j * 32 + n]);
            P[n] *= dA;
        }
    }
    float* o = ph + (((size_t)b * NCHUNK + s) * 192 + e) * 32;
    #pragma unroll
    for (int n = 0; n < DST; ++n) { o[n] = P[n]; o[16 + n] = h[n]; }
}

// K4 (pass B): sequential chunk combine; overwrites P-slot with chunk-start state.
__global__ __launch_bounds__(256) void k4_combine(float* __restrict__ ph)
{
    int g = blockIdx.x * 256 + threadIdx.x;
    int b = g / (192 * DST);
    int rem = g % (192 * DST);
    int e = rem / DST, n = rem % DST;
    float h = 0.0f;
    for (int s = 0; s < NCHUNK; ++s) {
        size_t ix = ((size_t)(b * NCHUNK + s) * 192 + e) * 32;
        float P = ph[ix + n];
        float hend = ph[ix + 16 + n];
        ph[ix + n] = h;
        h = fmaf(P, h, hend);
    }
}

// K5 (pass C): full scan with h_init; yraw = y + u*D written in-place over xc.
__global__ __launch_bounds__(192) void k5_scan_final(
    u16* __restrict__ xc,
    const float* __restrict__ dtbuf,
    const float* __restrict__ bcb,
    const float* __restrict__ dpw,
    const float* __restrict__ dpb,
    const float* __restrict__ alog,
    const float* __restrict__ Dp,
    const float* __restrict__ ph)
{
    __shared__ float dts[CLEN * 6];
    __shared__ float bcs[CLEN * 32];
    __shared__ u16 xcs[CLEN * 192];
    const int b = blockIdx.y, s = blockIdx.x, e = threadIdx.x;
    const size_t rb = (size_t)b * LSEQ + s * CLEN;
    for (int i = e; i < CLEN * 6; i += 192)  dts[i] = dtbuf[rb * 6 + i];
    for (int i = e; i < CLEN * 32; i += 192) bcs[i] = bcb[rb * 32 + i];
    {
        const u32* src = (const u32*)(xc + rb * DIN);
        u32* dd = (u32*)xcs;
        for (int i = e; i < 6144; i += 192) dd[i] = src[i];
    }
    float wr[6];
    #pragma unroll
    for (int r = 0; r < 6; ++r) wr[r] = dpw[e * 6 + r];
    const float bias = dpb[e];
    const float De = Dp[e];
    float m[DST];
    #pragma unroll
    for (int n = 0; n < DST; ++n) m[n] = -expf(alog[e * DST + n]);
    float h[DST];
    const float* hi = ph + (((size_t)b * NCHUNK + s) * 192 + e) * 32;
    #pragma unroll
    for (int n = 0; n < DST; ++n) h[n] = hi[n];
    __syncthreads();
    for (int j = 0; j < CLEN; ++j) {
        float u = b2f(xcs[j * 192 + e]);
        float xdt = bias;
        #pragma unroll
        for (int r = 0; r < 6; ++r) xdt = fmaf(dts[j * 6 + r], wr[r], xdt);
        float delta = softplus_f(xdt);
        float du = delta * u;
        float y = 0.0f;
        #pragma unroll
        for (int n = 0; n < DST; ++n) {
            float dA = expf(delta * m[n]);
            h[n] = fmaf(dA, h[n], du * bcs[j * 32 + n]);
            y = fmaf(h[n], bcs[j * 32 + 16 + n], y);
        }
        xc[(rb + j) * DIN + e] = f2b(y + u * De);
    }
}

// K6: gate (yraw*zs) staged swizzled -> out_proj (lane=row, wave-uniform scalar
// weights) -> LayerNorm(96) -> transposed store. grid (64,8), block 256. LDS 49.6 KB.
__global__ __launch_bounds__(256) void k6_gate_outproj_ln(
    const u16* __restrict__ yraw,   // (BL,192) bf16
    const u16* __restrict__ zsb,    // (BL,192) bf16
    const float* __restrict__ opw,  // (96,192)
    const float* __restrict__ gam,
    const float* __restrict__ bet,
    float* __restrict__ out)        // (8,96,4096)
{
    __shared__ u16 yt[64 * 192];    // gated, dword-swizzled
    __shared__ float ot[64 * 97];
    __shared__ float mu[64], rs[64];
    const int b = blockIdx.y, l0 = blockIdx.x * 64, tid = threadIdx.x;
    const int wv = __builtin_amdgcn_readfirstlane(tid >> 6);
    const int lane = tid & 63;
    const size_t base = ((size_t)b * LSEQ + l0) * DIN;
    const u32* yr = (const u32*)(yraw + base);
    const u32* zr = (const u32*)(zsb + base);
    u32* ytd = (u32*)yt;
    for (int i = tid; i < 6144; i += 256) {
        int row = i / 96, d = i % 96;
        u32 a = yr[i], z = zr[i];
        float y0 = b2f((u16)(a & 0xffff)) * b2f((u16)(z & 0xffff));
        float y1 = b2f((u16)(a >> 16)) * b2f((u16)(z >> 16));
        ytd[row * 96 + (((d >> 2) ^ (row & 7)) << 2) + (d & 3)] =
            (u32)f2b(y0) | ((u32)f2b(y1) << 16);
    }
    __syncthreads();
    {
        const int r7 = lane & 7;
        for (int g4 = 0; g4 < 6; ++g4) {
            int c0 = wv * 24 + g4 * 4;
            const float4* w0 = (const float4*)(opw + (size_t)(c0 + 0) * DIN);
            const float4* w1 = (const float4*)(opw + (size_t)(c0 + 1) * DIN);
            const float4* w2 = (const float4*)(opw + (size_t)(c0 + 2) * DIN);
            const float4* w3 = (const float4*)(opw + (size_t)(c0 + 3) * DIN);
            float a0 = 0, a1 = 0, a2 = 0, a3 = 0;
            #pragma unroll
            for (int g = 0; g < 24; ++g) {
                uint4 q = *(const uint4*)&ytd[lane * 96 + ((g ^ r7) << 2)];
                float u0 = b2f((u16)(q.x & 0xffff)), u1 = b2f((u16)(q.x >> 16));
                float u2 = b2f((u16)(q.y & 0xffff)), u3 = b2f((u16)(q.y >> 16));
                float u4 = b2f((u16)(q.z & 0xffff)), u5 = b2f((u16)(q.z >> 16));
                float u6 = b2f((u16)(q.w & 0xffff)), u7 = b2f((u16)(q.w >> 16));
                float4 p, r;
                p = w0[g * 2]; r = w0[g * 2 + 1];
                a0 = fmaf(u0,p.x,fmaf(u1,p.y,fmaf(u2,p.z,fmaf(u3,p.w,a0))));
                a0 = fmaf(u4,r.x,fmaf(u5,r.y,fmaf(u6,r.z,fmaf(u7,r.w,a0))));
                p = w1[g * 2]; r = w1[g * 2 + 1];
                a1 = fmaf(u0,p.x,fmaf(u1,p.y,fmaf(u2,p.z,fmaf(u3,p.w,a1))));
                a1 = fmaf(u4,r.x,fmaf(u5,r.y,fmaf(u6,r.z,fmaf(u7,r.w,a1))));
                p = w2[g * 2]; r = w2[g * 2 + 1];
                a2 = fmaf(u0,p.x,fmaf(u1,p.y,fmaf(u2,p.z,fmaf(u3,p.w,a2))));
                a2 = fmaf(u4,r.x,fmaf(u5,r.y,fmaf(u6,r.z,fmaf(u7,r.w,a2))));
                p = w3[g * 2]; r = w3[g * 2 + 1];
                a3 = fmaf(u0,p.x,fmaf(u1,p.y,fmaf(u2,p.z,fmaf(u3,p.w,a3))));
                a3 = fmaf(u4,r.x,fmaf(u5,r.y,fmaf(u6,r.z,fmaf(u7,r.w,a3))));
            }
            ot[lane * 97 + c0 + 0] = a0;
            ot[lane * 97 + c0 + 1] = a1;
            ot[lane * 97 + c0 + 2] = a2;
            ot[lane * 97 + c0 + 3] = a3;
        }
    }
    __syncthreads();
    if (tid < 64) {
        float s = 0.0f;
        for (int c = 0; c < 96; ++c) s += ot[tid * 97 + c];
        float mean = s * (1.0f / 96.0f);
        float v = 0.0f;
        for (int c = 0; c < 96; ++c) {
            float d = ot[tid * 97 + c] - mean;
            v = fmaf(d, d, v);
        }
        mu[tid] = mean;
        rs[tid] = rsqrtf(v * (1.0f / 96.0f) + 1e-5f);
    }
    __syncthreads();
    for (int idx = tid; idx < CDIM * 64; idx += 256) {
        int c = idx / 64, lr = idx % 64;
        float val = (ot[lr * 97 + c] - mu[lr]) * rs[lr] * gam[c] + bet[c];
        out[((size_t)b * CDIM + c) * LSEQ + l0 + lr] = val;
    }
}

extern "C" void kernel_launch(void* const* d_in, const int* in_sizes, int n_in,
                              void* d_out, int out_size, void* d_ws, size_t ws_size,
                              hipStream_t stream) {
    const float* x    = (const float*)d_in[0];
    const float* ipw  = (const float*)d_in[1];
    const float* cvw  = (const float*)d_in[2];
    const float* cvb  = (const float*)d_in[3];
    const float* xpw  = (const float*)d_in[4];
    const float* dpw  = (const float*)d_in[5];
    const float* dpb  = (const float*)d_in[6];
    const float* alog = (const float*)d_in[7];
    const float* Dp   = (const float*)d_in[8];
    const float* opw  = (const float*)d_in[9];
    const float* gam  = (const float*)d_in[10];
    const float* bet  = (const float*)d_in[11];
    float* out = (float*)d_out;

    // Workspace ~43 MB
    u16* xc    = (u16*)d_ws;                         // BL*192 bf16
    u16* zsb   = xc + (size_t)BL * DIN;              // BL*192 bf16
    float* dtb = (float*)(zsb + (size_t)BL * DIN);   // BL*6
    float* bcb = dtb + (size_t)BL * DTR;             // BL*32
    float* ph  = bcb + (size_t)BL * 32;              // B*64*192*32

    k1_front<<<dim3(LSEQ / 64, BATCH), 256, 0, stream>>>(
        x, ipw, cvw, cvb, xpw, xc, zsb, dtb, bcb);
    k3_scan_partial<<<dim3(NCHUNK, BATCH), 192, 0, stream>>>(
        xc, dtb, bcb, dpw, dpb, alog, ph);
    k4_combine<<<dim3(BATCH * 192 * DST / 256), 256, 0, stream>>>(ph);
    k5_scan_final<<<dim3(NCHUNK, BATCH), 192, 0, stream>>>(
        xc, dtb, bcb, dpw, dpb, alog, Dp, ph);
    k6_gate_outproj_ln<<<dim3(LSEQ / 64, BATCH), 256, 0, stream>>>(
        xc, zsb, opw, gam, bet, out);
}

// Round 6
// 505.815 us; speedup vs baseline: 1.0705x; 1.0705x over previous
//
#include <hip/hip_runtime.h>

#define BATCH   8
#define CDIM    96
#define LSEQ    4096
#define DIN     192
#define DTR     6
#define DST     16
#define NCHUNK  64
#define CLEN    64
#define BL      (BATCH*LSEQ)

typedef unsigned short u16;
typedef unsigned int   u32;

__device__ __forceinline__ float b2f(u16 u) {
    union { u32 i; float f; } v; v.i = ((u32)u) << 16; return v.f;
}
__device__ __forceinline__ u16 f2b(float f) {
    union { float f; u32 i; } v; v.f = f;
    u32 x = v.i;
    return (u16)((x + 0x7fffu + ((x >> 16) & 1u)) >> 16);
}
__device__ __forceinline__ float silu_f(float x) { return x / (1.0f + expf(-x)); }
__device__ __forceinline__ float softplus_f(float x) {
    return fmaxf(x, 0.0f) + log1pf(expf(-fabsf(x)));
}

// ---------------------------------------------------------------------------
// kA: in_proj, both halves. Weights in LDS (wave-uniform broadcast reads),
// activation row (K=96 fp32) in registers, lane = row. 4 chunks of 96 cols.
// x-half -> xm (bf16), z-half -> silu -> zs (bf16). grid (64,8), block 256.
// LDS 49.4 KB. No conv here -> no halo.
// ---------------------------------------------------------------------------
__global__ __launch_bounds__(256) void kA_inproj(
    const float* __restrict__ x,    // (8,96,4096)
    const float* __restrict__ ipw,  // (384,96)
    u16* __restrict__ xm,           // (BL,192) bf16
    u16* __restrict__ zs)           // (BL,192) bf16 silu(z)
{
    __shared__ float wch[96 * 96];  // weight chunk [c][k]
    __shared__ u32 xmt[64 * 49];    // bf16-pair out tile [row][48], stride 49
    const int b = blockIdx.y, l0 = blockIdx.x * 64, tid = threadIdx.x;
    const int wv = __builtin_amdgcn_readfirstlane(tid >> 6);
    const int lane = tid & 63;

    // u row in registers (coalesced: lanes read consecutive l)
    float u[96];
    #pragma unroll
    for (int k = 0; k < 96; ++k)
        u[k] = x[((size_t)b * CDIM + k) * LSEQ + l0 + lane];

    for (int q = 0; q < 4; ++q) {
        const float* wsrc = ipw + (size_t)q * 9216;
        for (int i = tid; i < 9216; i += 256) wch[i] = wsrc[i];
        __syncthreads();
        const int zh = q >> 1;
        for (int jp = 0; jp < 12; ++jp) {     // col pair within this wave's 24
            const float* w0 = &wch[(wv * 24 + jp * 2) * 96];
            const float* w1 = w0 + 96;
            float a0 = 0.0f, a1 = 0.0f;
            #pragma unroll
            for (int k4 = 0; k4 < 24; ++k4) {
                float4 wa = *(const float4*)(w0 + k4 * 4);
                float4 wb = *(const float4*)(w1 + k4 * 4);
                a0 = fmaf(u[k4*4+0], wa.x, a0); a1 = fmaf(u[k4*4+0], wb.x, a1);
                a0 = fmaf(u[k4*4+1], wa.y, a0); a1 = fmaf(u[k4*4+1], wb.y, a1);
                a0 = fmaf(u[k4*4+2], wa.z, a0); a1 = fmaf(u[k4*4+2], wb.z, a1);
                a0 = fmaf(u[k4*4+3], wa.w, a0); a1 = fmaf(u[k4*4+3], wb.w, a1);
            }
            if (zh) { a0 = silu_f(a0); a1 = silu_f(a1); }
            xmt[lane * 49 + wv * 12 + jp] = (u32)f2b(a0) | ((u32)f2b(a1) << 16);
        }
        __syncthreads();
        u16* dstbase = zh ? zs : xm;
        u32* gdst = (u32*)(dstbase + ((size_t)b * LSEQ + l0) * DIN);
        const int coff = (q & 1) * 48;
        for (int i = tid; i < 3072; i += 256) {
            int r = i / 48, jj = i % 48;
            gdst[(size_t)r * 96 + coff + jj] = xmt[r * 49 + jj];
        }
        __syncthreads();
    }
}

// ---------------------------------------------------------------------------
// kB: causal conv(4)+silu -> xc (bf16), then x_proj (K=192) -> dtb, bcb.
// xm tile (+3 halo rows) in LDS stride-97 (bank = lane+off, conflict-free),
// x_proj weights fp32 in LDS (broadcast), xc row in regs. grid (64,8), 256.
// LDS 59.0 KB.
// ---------------------------------------------------------------------------
__global__ __launch_bounds__(256) void kB_conv_xproj(
    const u16* __restrict__ xm,     // (BL,192) bf16
    const float* __restrict__ cvw,  // (192,4)
    const float* __restrict__ cvb,  // (192)
    const float* __restrict__ xpw,  // (38,192)
    u16* __restrict__ xc,           // (BL,192) bf16 silu(conv(xm))
    float* __restrict__ dtb,        // (BL,6)
    float* __restrict__ bcb)        // (BL,32) [B(16)|C(16)]
{
    __shared__ u32 tile[67 * 97];   // xm bf16-pairs [row][96], stride 97
    __shared__ float wxp[38 * 192];
    __shared__ float cwl[960];      // cvw (768) | cvb (192)
    const int b = blockIdx.y, l0 = blockIdx.x * 64, tid = threadIdx.x;
    const int wv = __builtin_amdgcn_readfirstlane(tid >> 6);
    const int lane = tid & 63;

    for (int i = tid; i < 67 * 96; i += 256) {
        int r = i / 96, d = i % 96, l = l0 - 3 + r;
        tile[r * 97 + d] =
            (l >= 0) ? ((const u32*)xm)[((size_t)b * LSEQ + l) * 96 + d] : 0u;
    }
    for (int i = tid; i < 38 * 192; i += 256) wxp[i] = xpw[i];
    for (int i = tid; i < 960; i += 256) cwl[i] = (i < 768) ? cvw[i] : cvb[i - 768];
    __syncthreads();

    // conv: output row = lane (l0+lane), channels wv*48..wv*48+47 (24 u32 pairs)
    u32 pk[24];
    #pragma unroll
    for (int p = 0; p < 24; ++p) {
        int dd = wv * 24 + p, ch = dd * 2;
        float a0 = cwl[768 + ch], a1 = cwl[768 + ch + 1];
        #pragma unroll
        for (int k = 0; k < 4; ++k) {
            u32 w2 = tile[(lane + k) * 97 + dd];
            a0 = fmaf(cwl[ch * 4 + k],     b2f((u16)(w2 & 0xffff)), a0);
            a1 = fmaf(cwl[ch * 4 + 4 + k], b2f((u16)(w2 >> 16)),    a1);
        }
        pk[p] = (u32)f2b(silu_f(a0)) | ((u32)f2b(silu_f(a1)) << 16);
    }
    __syncthreads();
    #pragma unroll
    for (int p = 0; p < 24; ++p) tile[lane * 97 + wv * 24 + p] = pk[p];
    __syncthreads();

    // xc -> global (coalesced) ; xc row -> registers
    u32* gxc = (u32*)(xc + ((size_t)b * LSEQ + l0) * DIN);
    for (int i = tid; i < 6144; i += 256) gxc[i] = tile[(i / 96) * 97 + i % 96];
    u32 xr[96];
    #pragma unroll
    for (int d = 0; d < 96; ++d) xr[d] = tile[lane * 97 + d];

    // x_proj: wave-strided cols, weights broadcast from LDS
    for (int c = wv; c < 38; c += 4) {
        const float* w = &wxp[c * 192];
        float a0 = 0.0f, a1 = 0.0f;
        #pragma unroll
        for (int d = 0; d < 96; ++d) {
            u32 v = xr[d];
            a0 = fmaf(b2f((u16)(v & 0xffff)), w[2 * d],     a0);
            a1 = fmaf(b2f((u16)(v >> 16)),    w[2 * d + 1], a1);
        }
        float a = a0 + a1;
        size_t rowg = (size_t)b * LSEQ + l0 + lane;
        if (c < DTR) dtb[rowg * DTR + c] = a;
        else         bcb[rowg * 32 + (c - DTR)] = a;
    }
}

// ---------------------------------------------------------------------------
// k3 (pass A): chunk-local scan with h0=0 -> ph [P(16)|hend(16)].
// ---------------------------------------------------------------------------
__global__ __launch_bounds__(192) void k3_scan_partial(
    const u16* __restrict__ xc,
    const float* __restrict__ dtbuf,
    const float* __restrict__ bcb,
    const float* __restrict__ dpw,   // (192,6)
    const float* __restrict__ dpb,   // (192)
    const float* __restrict__ alog,  // (192,16)
    float* __restrict__ ph)          // (B,NCHUNK,192,32)
{
    __shared__ float dts[CLEN * 6];
    __shared__ float bcs[CLEN * 32];
    __shared__ u16 xcs[CLEN * 192];
    const int b = blockIdx.y, s = blockIdx.x, e = threadIdx.x;
    const size_t rb = (size_t)b * LSEQ + s * CLEN;
    for (int i = e; i < CLEN * 6; i += 192)  dts[i] = dtbuf[rb * 6 + i];
    for (int i = e; i < CLEN * 32; i += 192) bcs[i] = bcb[rb * 32 + i];
    {
        const u32* src = (const u32*)(xc + rb * DIN);
        u32* dd = (u32*)xcs;
        for (int i = e; i < 6144; i += 192) dd[i] = src[i];
    }
    float wr[6];
    #pragma unroll
    for (int r = 0; r < 6; ++r) wr[r] = dpw[e * 6 + r];
    const float bias = dpb[e];
    float m[DST];
    #pragma unroll
    for (int n = 0; n < DST; ++n) m[n] = -expf(alog[e * DST + n]);
    float h[DST], P[DST];
    #pragma unroll
    for (int n = 0; n < DST; ++n) { h[n] = 0.0f; P[n] = 1.0f; }
    __syncthreads();
    for (int j = 0; j < CLEN; ++j) {
        float u = b2f(xcs[j * 192 + e]);
        float xdt = bias;
        #pragma unroll
        for (int r = 0; r < 6; ++r) xdt = fmaf(dts[j * 6 + r], wr[r], xdt);
        float delta = softplus_f(xdt);
        float du = delta * u;
        #pragma unroll
        for (int n = 0; n < DST; ++n) {
            float dA = expf(delta * m[n]);
            h[n] = fmaf(dA, h[n], du * bcs[j * 32 + n]);
            P[n] *= dA;
        }
    }
    float* o = ph + (((size_t)b * NCHUNK + s) * 192 + e) * 32;
    #pragma unroll
    for (int n = 0; n < DST; ++n) { o[n] = P[n]; o[16 + n] = h[n]; }
}

// ---------------------------------------------------------------------------
// k4 (pass B): sequential chunk combine, 4x-batched loads to break the
// load->fma latency chain. Overwrites P-slot with chunk-START state.
// ---------------------------------------------------------------------------
__global__ __launch_bounds__(256) void k4_combine(float* __restrict__ ph)
{
    int g = blockIdx.x * 256 + threadIdx.x;
    int b = g / (192 * DST);
    int rem = g % (192 * DST);
    int e = rem / DST, n = rem % DST;
    float h = 0.0f;
    for (int s = 0; s < NCHUNK; s += 4) {
        size_t ix0 = ((size_t)(b * NCHUNK + s) * 192 + e) * 32;
        float P[4], E[4];
        #pragma unroll
        for (int t = 0; t < 4; ++t) {
            P[t] = ph[ix0 + (size_t)t * 6144 + n];
            E[t] = ph[ix0 + (size_t)t * 6144 + 16 + n];
        }
        #pragma unroll
        for (int t = 0; t < 4; ++t) {
            ph[ix0 + (size_t)t * 6144 + n] = h;
            h = fmaf(P[t], h, E[t]);
        }
    }
}

// ---------------------------------------------------------------------------
// k5 (pass C): full scan with h_init; yraw = y + u*D written in-place over xc.
// ---------------------------------------------------------------------------
__global__ __launch_bounds__(192) void k5_scan_final(
    u16* __restrict__ xc,
    const float* __restrict__ dtbuf,
    const float* __restrict__ bcb,
    const float* __restrict__ dpw,
    const float* __restrict__ dpb,
    const float* __restrict__ alog,
    const float* __restrict__ Dp,
    const float* __restrict__ ph)
{
    __shared__ float dts[CLEN * 6];
    __shared__ float bcs[CLEN * 32];
    __shared__ u16 xcs[CLEN * 192];
    const int b = blockIdx.y, s = blockIdx.x, e = threadIdx.x;
    const size_t rb = (size_t)b * LSEQ + s * CLEN;
    for (int i = e; i < CLEN * 6; i += 192)  dts[i] = dtbuf[rb * 6 + i];
    for (int i = e; i < CLEN * 32; i += 192) bcs[i] = bcb[rb * 32 + i];
    {
        const u32* src = (const u32*)(xc + rb * DIN);
        u32* dd = (u32*)xcs;
        for (int i = e; i < 6144; i += 192) dd[i] = src[i];
    }
    float wr[6];
    #pragma unroll
    for (int r = 0; r < 6; ++r) wr[r] = dpw[e * 6 + r];
    const float bias = dpb[e];
    const float De = Dp[e];
    float m[DST];
    #pragma unroll
    for (int n = 0; n < DST; ++n) m[n] = -expf(alog[e * DST + n]);
    float h[DST];
    const float* hi = ph + (((size_t)b * NCHUNK + s) * 192 + e) * 32;
    #pragma unroll
    for (int n = 0; n < DST; ++n) h[n] = hi[n];
    __syncthreads();
    for (int j = 0; j < CLEN; ++j) {
        float u = b2f(xcs[j * 192 + e]);
        float xdt = bias;
        #pragma unroll
        for (int r = 0; r < 6; ++r) xdt = fmaf(dts[j * 6 + r], wr[r], xdt);
        float delta = softplus_f(xdt);
        float du = delta * u;
        float y = 0.0f;
        #pragma unroll
        for (int n = 0; n < DST; ++n) {
            float dA = expf(delta * m[n]);
            h[n] = fmaf(dA, h[n], du * bcs[j * 32 + n]);
            y = fmaf(h[n], bcs[j * 32 + 16 + n], y);
        }
        xc[(rb + j) * DIN + e] = f2b(y + u * De);
    }
}

// ---------------------------------------------------------------------------
// k6: gate (yraw*zs) -> stride-97 LDS -> row in regs -> out_proj with fp32
// weights in LDS (2 chunks of 48 cols, broadcast) -> LN(96) -> transposed
// store. ot reuses the yt LDS region. grid (64,8), 256. LDS 62.2 KB.
// ---------------------------------------------------------------------------
__global__ __launch_bounds__(256) void k6_gate_outproj_ln(
    const u16* __restrict__ yraw,   // (BL,192) bf16
    const u16* __restrict__ zsb,    // (BL,192) bf16
    const float* __restrict__ opw,  // (96,192)
    const float* __restrict__ gam,
    const float* __restrict__ bet,
    float* __restrict__ out)        // (8,96,4096)
{
    __shared__ u32 yt[64 * 97];     // gated bf16-pairs; later reused as ot fp32
    __shared__ float wop[48 * 192];
    __shared__ float mu[64], rs[64];
    const int b = blockIdx.y, l0 = blockIdx.x * 64, tid = threadIdx.x;
    const int wv = __builtin_amdgcn_readfirstlane(tid >> 6);
    const int lane = tid & 63;
    const u32* yr = (const u32*)(yraw + ((size_t)b * LSEQ + l0) * DIN);
    const u32* zr = (const u32*)(zsb + ((size_t)b * LSEQ + l0) * DIN);
    for (int i = tid; i < 6144; i += 256) {
        u32 a = yr[i], z = zr[i];
        float y0 = b2f((u16)(a & 0xffff)) * b2f((u16)(z & 0xffff));
        float y1 = b2f((u16)(a >> 16)) * b2f((u16)(z >> 16));
        yt[(i / 96) * 97 + i % 96] = (u32)f2b(y0) | ((u32)f2b(y1) << 16);
    }
    __syncthreads();
    u32 vr[96];
    #pragma unroll
    for (int d = 0; d < 96; ++d) vr[d] = yt[lane * 97 + d];
    __syncthreads();   // all vr loads done before ot overwrites yt
    float* ot = (float*)yt;
    for (int half = 0; half < 2; ++half) {
        const float* wsrc = opw + (size_t)half * 9216;
        for (int i = tid; i < 9216; i += 256) wop[i] = wsrc[i];
        __syncthreads();
        for (int j = 0; j < 12; ++j) {
            int lc = wv * 12 + j;
            const float* w = &wop[lc * 192];
            float a0 = 0.0f, a1 = 0.0f;
            #pragma unroll
            for (int d = 0; d < 96; ++d) {
                u32 v = vr[d];
                a0 = fmaf(b2f((u16)(v & 0xffff)), w[2 * d],     a0);
                a1 = fmaf(b2f((u16)(v >> 16)),    w[2 * d + 1], a1);
            }
            ot[lane * 97 + half * 48 + lc] = a0 + a1;
        }
        __syncthreads();
    }
    if (tid < 64) {
        float s = 0.0f;
        for (int c = 0; c < 96; ++c) s += ot[tid * 97 + c];
        float mean = s * (1.0f / 96.0f);
        float v = 0.0f;
        for (int c = 0; c < 96; ++c) {
            float d = ot[tid * 97 + c] - mean;
            v = fmaf(d, d, v);
        }
        mu[tid] = mean;
        rs[tid] = rsqrtf(v * (1.0f / 96.0f) + 1e-5f);
    }
    __syncthreads();
    for (int idx = tid; idx < 6144; idx += 256) {
        int c = idx / 64, lr = idx % 64;
        float val = (ot[lr * 97 + c] - mu[lr]) * rs[lr] * gam[c] + bet[c];
        out[((size_t)b * CDIM + c) * LSEQ + l0 + lr] = val;
    }
}

extern "C" void kernel_launch(void* const* d_in, const int* in_sizes, int n_in,
                              void* d_out, int out_size, void* d_ws, size_t ws_size,
                              hipStream_t stream) {
    const float* x    = (const float*)d_in[0];
    const float* ipw  = (const float*)d_in[1];
    const float* cvw  = (const float*)d_in[2];
    const float* cvb  = (const float*)d_in[3];
    const float* xpw  = (const float*)d_in[4];
    const float* dpw  = (const float*)d_in[5];
    const float* dpb  = (const float*)d_in[6];
    const float* alog = (const float*)d_in[7];
    const float* Dp   = (const float*)d_in[8];
    const float* opw  = (const float*)d_in[9];
    const float* gam  = (const float*)d_in[10];
    const float* bet  = (const float*)d_in[11];
    float* out = (float*)d_out;

    // Workspace 42.8 MB. xm dead after kB, ph (same 12.6 MB size) aliases it.
    u16* xm    = (u16*)d_ws;                         // BL*192 bf16 (-> ph later)
    u16* zsb   = xm + (size_t)BL * DIN;              // BL*192 bf16
    u16* xc    = zsb + (size_t)BL * DIN;             // BL*192 bf16 (-> yraw)
    float* dtb = (float*)(xc + (size_t)BL * DIN);    // BL*6
    float* bcb = dtb + (size_t)BL * DTR;             // BL*32
    float* ph  = (float*)xm;                         // B*64*192*32 f32 == 12.6 MB

    kA_inproj<<<dim3(LSEQ / 64, BATCH), 256, 0, stream>>>(x, ipw, xm, zsb);
    kB_conv_xproj<<<dim3(LSEQ / 64, BATCH), 256, 0, stream>>>(
        xm, cvw, cvb, xpw, xc, dtb, bcb);
    k3_scan_partial<<<dim3(NCHUNK, BATCH), 192, 0, stream>>>(
        xc, dtb, bcb, dpw, dpb, alog, ph);
    k4_combine<<<dim3(BATCH * 192 * DST / 256), 256, 0, stream>>>(ph);
    k5_scan_final<<<dim3(NCHUNK, BATCH), 192, 0, stream>>>(
        xc, dtb, bcb, dpw, dpb, alog, Dp, ph);
    k6_gate_outproj_ln<<<dim3(LSEQ / 64, BATCH), 256, 0, stream>>>(
        xc, zsb, opw, gam, bet, out);
}

// Round 7
// 318.226 us; speedup vs baseline: 1.7015x; 1.5895x over previous
//
#include <hip/hip_runtime.h>

#define BATCH   8
#define CDIM    96
#define LSEQ    4096
#define DIN     192
#define DTR     6
#define DST     16
#define NCHUNK  64
#define CLEN    64
#define BL      (BATCH*LSEQ)

typedef unsigned short u16;
typedef unsigned int   u32;

__device__ __forceinline__ float b2f(u16 u) {
    union { u32 i; float f; } v; v.i = ((u32)u) << 16; return v.f;
}
__device__ __forceinline__ u16 f2b(float f) {
    union { float f; u32 i; } v; v.f = f;
    u32 x = v.i;
    return (u16)((x + 0x7fffu + ((x >> 16) & 1u)) >> 16);
}
// fast transcendentals: v_exp_f32 / v_log_f32 (rel err ~1e-6, fine vs 0.0234 abs budget)
__device__ __forceinline__ float silu_f(float x) { return x / (1.0f + __expf(-x)); }
__device__ __forceinline__ float softplus_f(float x) {
    return fmaxf(x, 0.0f) + __logf(1.0f + __expf(-fabsf(x)));
}

// ---------------------------------------------------------------------------
// kA: in_proj, both halves. Weights fp32 in LDS (wave-uniform broadcast),
// u row (K=96 fp32) in registers, lane = row. 4 chunks of 96 cols.
// grid (64,8), block 256. LDS 49.4 KB.
// ---------------------------------------------------------------------------
__global__ __launch_bounds__(256) void kA_inproj(
    const float* __restrict__ x,    // (8,96,4096)
    const float* __restrict__ ipw,  // (384,96)
    u16* __restrict__ xm,           // (BL,192) bf16
    u16* __restrict__ zs)           // (BL,192) bf16 silu(z)
{
    __shared__ float wch[96 * 96];
    __shared__ u32 xmt[64 * 49];
    const int b = blockIdx.y, l0 = blockIdx.x * 64, tid = threadIdx.x;
    const int wv = __builtin_amdgcn_readfirstlane(tid >> 6);
    const int lane = tid & 63;

    float u[96];
    #pragma unroll
    for (int k = 0; k < 96; ++k)
        u[k] = x[((size_t)b * CDIM + k) * LSEQ + l0 + lane];

    for (int q = 0; q < 4; ++q) {
        const float* wsrc = ipw + (size_t)q * 9216;
        for (int i = tid; i < 9216; i += 256) wch[i] = wsrc[i];
        __syncthreads();
        const int zh = q >> 1;
        for (int jp = 0; jp < 12; ++jp) {
            const float* w0 = &wch[(wv * 24 + jp * 2) * 96];
            const float* w1 = w0 + 96;
            float a0 = 0.0f, a1 = 0.0f;
            #pragma unroll
            for (int k4 = 0; k4 < 24; ++k4) {
                float4 wa = *(const float4*)(w0 + k4 * 4);
                float4 wb = *(const float4*)(w1 + k4 * 4);
                a0 = fmaf(u[k4*4+0], wa.x, a0); a1 = fmaf(u[k4*4+0], wb.x, a1);
                a0 = fmaf(u[k4*4+1], wa.y, a0); a1 = fmaf(u[k4*4+1], wb.y, a1);
                a0 = fmaf(u[k4*4+2], wa.z, a0); a1 = fmaf(u[k4*4+2], wb.z, a1);
                a0 = fmaf(u[k4*4+3], wa.w, a0); a1 = fmaf(u[k4*4+3], wb.w, a1);
            }
            if (zh) { a0 = silu_f(a0); a1 = silu_f(a1); }
            xmt[lane * 49 + wv * 12 + jp] = (u32)f2b(a0) | ((u32)f2b(a1) << 16);
        }
        __syncthreads();
        u16* dstbase = zh ? zs : xm;
        u32* gdst = (u32*)(dstbase + ((size_t)b * LSEQ + l0) * DIN);
        const int coff = (q & 1) * 48;
        for (int i = tid; i < 3072; i += 256) {
            int r = i / 48, jj = i % 48;
            gdst[(size_t)r * 96 + coff + jj] = xmt[r * 49 + jj];
        }
        __syncthreads();
    }
}

// ---------------------------------------------------------------------------
// kB: causal conv(4)+silu -> xc, then x_proj (K=192, chunked 24-pair register
// slices to bound VGPR). LDS 59 KB. grid (64,8), block 256.
// ---------------------------------------------------------------------------
__global__ __launch_bounds__(256) void kB_conv_xproj(
    const u16* __restrict__ xm,
    const float* __restrict__ cvw,  // (192,4)
    const float* __restrict__ cvb,  // (192)
    const float* __restrict__ xpw,  // (38,192)
    u16* __restrict__ xc,           // (BL,192) bf16
    float* __restrict__ dtb,        // (BL,6)
    float* __restrict__ bcb)        // (BL,32)
{
    __shared__ u32 tile[67 * 97];
    __shared__ float wxp[38 * 192];
    __shared__ float cwl[960];
    const int b = blockIdx.y, l0 = blockIdx.x * 64, tid = threadIdx.x;
    const int wv = __builtin_amdgcn_readfirstlane(tid >> 6);
    const int lane = tid & 63;

    for (int i = tid; i < 67 * 96; i += 256) {
        int r = i / 96, d = i % 96, l = l0 - 3 + r;
        tile[r * 97 + d] =
            (l >= 0) ? ((const u32*)xm)[((size_t)b * LSEQ + l) * 96 + d] : 0u;
    }
    for (int i = tid; i < 38 * 192; i += 256) wxp[i] = xpw[i];
    for (int i = tid; i < 960; i += 256) cwl[i] = (i < 768) ? cvw[i] : cvb[i - 768];
    __syncthreads();

    // conv: row = lane, channels wv*48..+47 (24 u32 pairs)
    u32 pk[24];
    #pragma unroll
    for (int p = 0; p < 24; ++p) {
        int dd = wv * 24 + p, ch = dd * 2;
        float a0 = cwl[768 + ch], a1 = cwl[768 + ch + 1];
        #pragma unroll
        for (int k = 0; k < 4; ++k) {
            u32 w2 = tile[(lane + k) * 97 + dd];
            a0 = fmaf(cwl[ch * 4 + k],     b2f((u16)(w2 & 0xffff)), a0);
            a1 = fmaf(cwl[ch * 4 + 4 + k], b2f((u16)(w2 >> 16)),    a1);
        }
        pk[p] = (u32)f2b(silu_f(a0)) | ((u32)f2b(silu_f(a1)) << 16);
    }
    __syncthreads();
    #pragma unroll
    for (int p = 0; p < 24; ++p) tile[lane * 97 + wv * 24 + p] = pk[p];
    __syncthreads();

    u32* gxc = (u32*)(xc + ((size_t)b * LSEQ + l0) * DIN);
    for (int i = tid; i < 6144; i += 256) gxc[i] = tile[(i / 96) * 97 + i % 96];

    // x_proj: cols c = wv + 4t; K in 4 chunks of 24 pairs kept in registers
    float acc0[10], acc1[10];
    #pragma unroll
    for (int t = 0; t < 10; ++t) { acc0[t] = 0.0f; acc1[t] = 0.0f; }
    for (int ch = 0; ch < 4; ++ch) {
        u32 vv[24];
        #pragma unroll
        for (int p = 0; p < 24; ++p) vv[p] = tile[lane * 97 + ch * 24 + p];
        #pragma unroll
        for (int t = 0; t < 10; ++t) {
            int c = wv + 4 * t;
            if (c < 38) {
                const float* w = &wxp[c * 192 + ch * 48];
                #pragma unroll
                for (int p = 0; p < 24; ++p) {
                    float2 wp = *(const float2*)(w + 2 * p);
                    acc0[t] = fmaf(b2f((u16)(vv[p] & 0xffff)), wp.x, acc0[t]);
                    acc1[t] = fmaf(b2f((u16)(vv[p] >> 16)),    wp.y, acc1[t]);
                }
            }
        }
    }
    size_t rowg = (size_t)b * LSEQ + l0 + lane;
    #pragma unroll
    for (int t = 0; t < 10; ++t) {
        int c = wv + 4 * t;
        if (c < 38) {
            float a = acc0[t] + acc1[t];
            if (c < DTR) dtb[rowg * DTR + c] = a;
            else         bcb[rowg * 32 + (c - DTR)] = a;
        }
    }
}

// ---------------------------------------------------------------------------
// k3 (pass A): chunk-local scan with h0=0 -> ph [P(16)|hend(16)].
// ---------------------------------------------------------------------------
__global__ __launch_bounds__(192) void k3_scan_partial(
    const u16* __restrict__ xc,
    const float* __restrict__ dtbuf,
    const float* __restrict__ bcb,
    const float* __restrict__ dpw,
    const float* __restrict__ dpb,
    const float* __restrict__ alog,
    float* __restrict__ ph)
{
    __shared__ float dts[CLEN * 6];
    __shared__ float bcs[CLEN * 32];
    __shared__ u16 xcs[CLEN * 192];
    const int b = blockIdx.y, s = blockIdx.x, e = threadIdx.x;
    const size_t rb = (size_t)b * LSEQ + s * CLEN;
    for (int i = e; i < CLEN * 6; i += 192)  dts[i] = dtbuf[rb * 6 + i];
    for (int i = e; i < CLEN * 32; i += 192) bcs[i] = bcb[rb * 32 + i];
    {
        const u32* src = (const u32*)(xc + rb * DIN);
        u32* dd = (u32*)xcs;
        for (int i = e; i < 6144; i += 192) dd[i] = src[i];
    }
    float wr[6];
    #pragma unroll
    for (int r = 0; r < 6; ++r) wr[r] = dpw[e * 6 + r];
    const float bias = dpb[e];
    float m[DST];
    #pragma unroll
    for (int n = 0; n < DST; ++n) m[n] = -__expf(alog[e * DST + n]);
    float h[DST], P[DST];
    #pragma unroll
    for (int n = 0; n < DST; ++n) { h[n] = 0.0f; P[n] = 1.0f; }
    __syncthreads();
    for (int j = 0; j < CLEN; ++j) {
        float u = b2f(xcs[j * 192 + e]);
        float xdt = bias;
        #pragma unroll
        for (int r = 0; r < 6; ++r) xdt = fmaf(dts[j * 6 + r], wr[r], xdt);
        float delta = softplus_f(xdt);
        float du = delta * u;
        #pragma unroll
        for (int n = 0; n < DST; ++n) {
            float dA = __expf(delta * m[n]);
            h[n] = fmaf(dA, h[n], du * bcs[j * 32 + n]);
            P[n] *= dA;
        }
    }
    float* o = ph + (((size_t)b * NCHUNK + s) * 192 + e) * 32;
    #pragma unroll
    for (int n = 0; n < DST; ++n) { o[n] = P[n]; o[16 + n] = h[n]; }
}

// ---------------------------------------------------------------------------
// k4 (pass B): sequential chunk combine, 4x-batched loads.
// ---------------------------------------------------------------------------
__global__ __launch_bounds__(256) void k4_combine(float* __restrict__ ph)
{
    int g = blockIdx.x * 256 + threadIdx.x;
    int b = g / (192 * DST);
    int rem = g % (192 * DST);
    int e = rem / DST, n = rem % DST;
    float h = 0.0f;
    for (int s = 0; s < NCHUNK; s += 4) {
        size_t ix0 = ((size_t)(b * NCHUNK + s) * 192 + e) * 32;
        float P[4], E[4];
        #pragma unroll
        for (int t = 0; t < 4; ++t) {
            P[t] = ph[ix0 + (size_t)t * 6144 + n];
            E[t] = ph[ix0 + (size_t)t * 6144 + 16 + n];
        }
        #pragma unroll
        for (int t = 0; t < 4; ++t) {
            ph[ix0 + (size_t)t * 6144 + n] = h;
            h = fmaf(P[t], h, E[t]);
        }
    }
}

// ---------------------------------------------------------------------------
// k5 (pass C): full scan with h_init; yraw = y + u*D in-place over xc.
// ---------------------------------------------------------------------------
__global__ __launch_bounds__(192) void k5_scan_final(
    u16* __restrict__ xc,
    const float* __restrict__ dtbuf,
    const float* __restrict__ bcb,
    const float* __restrict__ dpw,
    const float* __restrict__ dpb,
    const float* __restrict__ alog,
    const float* __restrict__ Dp,
    const float* __restrict__ ph)
{
    __shared__ float dts[CLEN * 6];
    __shared__ float bcs[CLEN * 32];
    __shared__ u16 xcs[CLEN * 192];
    const int b = blockIdx.y, s = blockIdx.x, e = threadIdx.x;
    const size_t rb = (size_t)b * LSEQ + s * CLEN;
    for (int i = e; i < CLEN * 6; i += 192)  dts[i] = dtbuf[rb * 6 + i];
    for (int i = e; i < CLEN * 32; i += 192) bcs[i] = bcb[rb * 32 + i];
    {
        const u32* src = (const u32*)(xc + rb * DIN);
        u32* dd = (u32*)xcs;
        for (int i = e; i < 6144; i += 192) dd[i] = src[i];
    }
    float wr[6];
    #pragma unroll
    for (int r = 0; r < 6; ++r) wr[r] = dpw[e * 6 + r];
    const float bias = dpb[e];
    const float De = Dp[e];
    float m[DST];
    #pragma unroll
    for (int n = 0; n < DST; ++n) m[n] = -__expf(alog[e * DST + n]);
    float h[DST];
    const float* hi = ph + (((size_t)b * NCHUNK + s) * 192 + e) * 32;
    #pragma unroll
    for (int n = 0; n < DST; ++n) h[n] = hi[n];
    __syncthreads();
    for (int j = 0; j < CLEN; ++j) {
        float u = b2f(xcs[j * 192 + e]);
        float xdt = bias;
        #pragma unroll
        for (int r = 0; r < 6; ++r) xdt = fmaf(dts[j * 6 + r], wr[r], xdt);
        float delta = softplus_f(xdt);
        float du = delta * u;
        float y = 0.0f;
        #pragma unroll
        for (int n = 0; n < DST; ++n) {
            float dA = __expf(delta * m[n]);
            h[n] = fmaf(dA, h[n], du * bcs[j * 32 + n]);
            y = fmaf(h[n], bcs[j * 32 + 16 + n], y);
        }
        xc[(rb + j) * DIN + e] = f2b(y + u * De);
    }
}

// ---------------------------------------------------------------------------
// k6: gate -> yt LDS (u32 stride-100, b128-friendly) -> out_proj (results in
// 24 regs, weights fp32 LDS broadcast, 2 halves) -> ot reuses yt region
// (fp32 stride-97) -> LN(96) -> transposed store. LDS 61.5 KB. No reg row.
// ---------------------------------------------------------------------------
__global__ __launch_bounds__(256) void k6_gate_outproj_ln(
    const u16* __restrict__ yraw,
    const u16* __restrict__ zsb,
    const float* __restrict__ opw,  // (96,192)
    const float* __restrict__ gam,
    const float* __restrict__ bet,
    float* __restrict__ out)        // (8,96,4096)
{
    __shared__ __align__(16) char smem[25600 + 36864 + 512];
    u32* yt = (u32*)smem;                       // [64][100] gated bf16-pairs
    float* wop = (float*)(smem + 25600);        // [48][192]
    float* mu = (float*)(smem + 25600 + 36864); // [64]
    float* rs = mu + 64;                        // [64]
    float* ot = (float*)smem;                   // [64][97] fp32 (reuse)
    const int b = blockIdx.y, l0 = blockIdx.x * 64, tid = threadIdx.x;
    const int wv = __builtin_amdgcn_readfirstlane(tid >> 6);
    const int lane = tid & 63;
    const u32* yr = (const u32*)(yraw + ((size_t)b * LSEQ + l0) * DIN);
    const u32* zr = (const u32*)(zsb + ((size_t)b * LSEQ + l0) * DIN);
    for (int i = tid; i < 6144; i += 256) {
        u32 a = yr[i], z = zr[i];
        float y0 = b2f((u16)(a & 0xffff)) * b2f((u16)(z & 0xffff));
        float y1 = b2f((u16)(a >> 16)) * b2f((u16)(z >> 16));
        yt[(i / 96) * 100 + i % 96] = (u32)f2b(y0) | ((u32)f2b(y1) << 16);
    }
    __syncthreads();
    float rc[24];
    for (int half = 0; half < 2; ++half) {
        const float* wsrc = opw + (size_t)half * 9216;
        for (int i = tid; i < 9216; i += 256) wop[i] = wsrc[i];
        __syncthreads();
        for (int jp = 0; jp < 6; ++jp) {
            int lc = wv * 12 + jp * 2;
            const float4* w0 = (const float4*)&wop[lc * 192];
            const float4* w1 = (const float4*)&wop[(lc + 1) * 192];
            float a0 = 0.0f, a1 = 0.0f;
            #pragma unroll
            for (int k4 = 0; k4 < 24; ++k4) {
                uint4 q = *(const uint4*)&yt[lane * 100 + k4 * 4];
                float y0 = b2f((u16)(q.x & 0xffff)), y1 = b2f((u16)(q.x >> 16));
                float y2 = b2f((u16)(q.y & 0xffff)), y3 = b2f((u16)(q.y >> 16));
                float y4 = b2f((u16)(q.z & 0xffff)), y5 = b2f((u16)(q.z >> 16));
                float y6 = b2f((u16)(q.w & 0xffff)), y7 = b2f((u16)(q.w >> 16));
                float4 p = w0[k4 * 2], r = w0[k4 * 2 + 1];
                a0 = fmaf(y0,p.x,fmaf(y1,p.y,fmaf(y2,p.z,fmaf(y3,p.w,a0))));
                a0 = fmaf(y4,r.x,fmaf(y5,r.y,fmaf(y6,r.z,fmaf(y7,r.w,a0))));
                p = w1[k4 * 2]; r = w1[k4 * 2 + 1];
                a1 = fmaf(y0,p.x,fmaf(y1,p.y,fmaf(y2,p.z,fmaf(y3,p.w,a1))));
                a1 = fmaf(y4,r.x,fmaf(y5,r.y,fmaf(y6,r.z,fmaf(y7,r.w,a1))));
            }
            rc[half * 12 + jp * 2]     = a0;
            rc[half * 12 + jp * 2 + 1] = a1;
        }
        __syncthreads();   // wop restage safety (and yt-read completion on last)
    }
    #pragma unroll
    for (int t = 0; t < 24; ++t) {
        int c = (t / 12) * 48 + wv * 12 + (t % 12);
        ot[lane * 97 + c] = rc[t];
    }
    __syncthreads();
    if (tid < 64) {
        float s = 0.0f;
        for (int c = 0; c < 96; ++c) s += ot[tid * 97 + c];
        float mean = s * (1.0f / 96.0f);
        float v = 0.0f;
        for (int c = 0; c < 96; ++c) {
            float d = ot[tid * 97 + c] - mean;
            v = fmaf(d, d, v);
        }
        mu[tid] = mean;
        rs[tid] = rsqrtf(v * (1.0f / 96.0f) + 1e-5f);
    }
    __syncthreads();
    for (int idx = tid; idx < 6144; idx += 256) {
        int c = idx / 64, lr = idx % 64;
        float val = (ot[lr * 97 + c] - mu[lr]) * rs[lr] * gam[c] + bet[c];
        out[((size_t)b * CDIM + c) * LSEQ + l0 + lr] = val;
    }
}

extern "C" void kernel_launch(void* const* d_in, const int* in_sizes, int n_in,
                              void* d_out, int out_size, void* d_ws, size_t ws_size,
                              hipStream_t stream) {
    const float* x    = (const float*)d_in[0];
    const float* ipw  = (const float*)d_in[1];
    const float* cvw  = (const float*)d_in[2];
    const float* cvb  = (const float*)d_in[3];
    const float* xpw  = (const float*)d_in[4];
    const float* dpw  = (const float*)d_in[5];
    const float* dpb  = (const float*)d_in[6];
    const float* alog = (const float*)d_in[7];
    const float* Dp   = (const float*)d_in[8];
    const float* opw  = (const float*)d_in[9];
    const float* gam  = (const float*)d_in[10];
    const float* bet  = (const float*)d_in[11];
    float* out = (float*)d_out;

    // Workspace 42.8 MB. xm dead after kB; ph aliases it (same 12.6 MB).
    u16* xm    = (u16*)d_ws;
    u16* zsb   = xm + (size_t)BL * DIN;
    u16* xc    = zsb + (size_t)BL * DIN;
    float* dtb = (float*)(xc + (size_t)BL * DIN);
    float* bcb = dtb + (size_t)BL * DTR;
    float* ph  = (float*)xm;

    kA_inproj<<<dim3(LSEQ / 64, BATCH), 256, 0, stream>>>(x, ipw, xm, zsb);
    kB_conv_xproj<<<dim3(LSEQ / 64, BATCH), 256, 0, stream>>>(
        xm, cvw, cvb, xpw, xc, dtb, bcb);
    k3_scan_partial<<<dim3(NCHUNK, BATCH), 192, 0, stream>>>(
        xc, dtb, bcb, dpw, dpb, alog, ph);
    k4_combine<<<dim3(BATCH * 192 * DST / 256), 256, 0, stream>>>(ph);
    k5_scan_final<<<dim3(NCHUNK, BATCH), 192, 0, stream>>>(
        xc, dtb, bcb, dpw, dpb, alog, Dp, ph);
    k6_gate_outproj_ln<<<dim3(LSEQ / 64, BATCH), 256, 0, stream>>>(
        xc, zsb, opw, gam, bet, out);
}

// Round 8
// 261.515 us; speedup vs baseline: 2.0705x; 1.2169x over previous
//
#include <hip/hip_runtime.h>

#define BATCH   8
#define CDIM    96
#define LSEQ    4096
#define DIN     192
#define DTR     6
#define DST     16
#define NCHUNK  64
#define CLEN    64
#define BL      (BATCH*LSEQ)

typedef unsigned short u16;
typedef unsigned int   u32;
typedef __attribute__((ext_vector_type(8))) short bf16x8;
typedef __attribute__((ext_vector_type(4))) float f32x4;

__device__ __forceinline__ float b2f(u16 u) {
    union { u32 i; float f; } v; v.i = ((u32)u) << 16; return v.f;
}
__device__ __forceinline__ u16 f2b(float f) {
    union { float f; u32 i; } v; v.f = f;
    u32 x = v.i;
    return (u16)((x + 0x7fffu + ((x >> 16) & 1u)) >> 16);
}
// pack high halves of two fp32 -> bf16 pair (truncation; 2 VALU)
__device__ __forceinline__ u32 pkhi(float a, float b) {
    union { float f; u32 i; } ua, ub; ua.f = a; ub.f = b;
    return (ua.i >> 16) | (ub.i & 0xffff0000u);
}
__device__ __forceinline__ float silu_f(float x) { return x / (1.0f + __expf(-x)); }
__device__ __forceinline__ float softplus_f(float x) {
    return fmaxf(x, 0.0f) + __logf(1.0f + __expf(-fabsf(x)));
}

// ---------------------------------------------------------------------------
// kA: in_proj via MFMA bf16 16x16x32. Block = 64 rows x 384 cols, K=96.
// Wave w owns 96 output cols (w0,1 -> xm halves; w2,3 -> silu -> zs halves).
// A (u-tile) bf16 in LDS stride-50 u32; B read from global fp32 -> bf16 pack.
// grid (64,8), block 256. LDS 12.8 KB.
// ---------------------------------------------------------------------------
__global__ __launch_bounds__(256) void kA_inproj(
    const float* __restrict__ x,    // (8,96,4096)
    const float* __restrict__ ipw,  // (384,96)
    u16* __restrict__ xm,           // (BL,192) bf16
    u16* __restrict__ zs)           // (BL,192) bf16 silu(z)
{
    __shared__ u32 uA[64 * 50];     // bf16 pairs [l][k/2], stride 50
    const int b = blockIdx.y, l0 = blockIdx.x * 64, tid = threadIdx.x;
    const int wv = tid >> 6, lane = tid & 63;
    const int m16 = lane & 15, quad = lane >> 4;

    // stage A: coalesced fp32 reads (lane = l), RNE-pack to bf16 pairs
    for (int idx = tid; idx < 48 * 64; idx += 256) {
        int k2 = idx >> 6, l = idx & 63;
        float f0 = x[((size_t)b * CDIM + 2 * k2) * LSEQ + l0 + l];
        float f1 = x[((size_t)b * CDIM + 2 * k2 + 1) * LSEQ + l0 + l];
        uA[l * 50 + k2] = (u32)f2b(f0) | ((u32)f2b(f1) << 16);
    }
    __syncthreads();

    const int zh = wv >> 1;           // wave-uniform
    const int cb = (wv & 1) * 96;     // col base within 192-wide dest row
    f32x4 acc[4][6];
    #pragma unroll
    for (int mt = 0; mt < 4; ++mt)
        #pragma unroll
        for (int nt = 0; nt < 6; ++nt)
            acc[mt][nt] = (f32x4){0.0f, 0.0f, 0.0f, 0.0f};

    #pragma unroll
    for (int kt = 0; kt < 3; ++kt) {
        const int k0 = kt * 32;
        // A-fragments: A[m = lane&15][k = quad*8 + j]
        bf16x8 am[4];
        #pragma unroll
        for (int mt = 0; mt < 4; ++mt) {
            int row = mt * 16 + m16;
            const u32* ap = &uA[row * 50 + (k0 >> 1) + quad * 4];
            union { bf16x8 v; uint4 u; } t;
            t.u.x = ap[0]; t.u.y = ap[1]; t.u.z = ap[2]; t.u.w = ap[3];
            am[mt] = t.v;
        }
        // B-fragments: B[k = quad*8 + j][n = lane&15]; B[k][n] = ipw[ncol][k]
        bf16x8 bn[6];
        #pragma unroll
        for (int nt = 0; nt < 6; ++nt) {
            int ncol = wv * 96 + nt * 16 + m16;
            const float* wp = ipw + (size_t)ncol * 96 + k0 + quad * 8;
            float4 wa = *(const float4*)wp;
            float4 wb = *(const float4*)(wp + 4);
            union { bf16x8 v; u32 u[4]; } t;
            t.u[0] = pkhi(wa.x, wa.y);
            t.u[1] = pkhi(wa.z, wa.w);
            t.u[2] = pkhi(wb.x, wb.y);
            t.u[3] = pkhi(wb.z, wb.w);
            bn[nt] = t.v;
        }
        #pragma unroll
        for (int mt = 0; mt < 4; ++mt)
            #pragma unroll
            for (int nt = 0; nt < 6; ++nt)
                acc[mt][nt] = __builtin_amdgcn_mfma_f32_16x16x32_bf16(
                    am[mt], bn[nt], acc[mt][nt], 0, 0, 0);
    }

    // epilogue: D row = quad*4 + r, col = lane&15 within each 16x16 tile
    u16* dstbase = zh ? zs : xm;
    #pragma unroll
    for (int mt = 0; mt < 4; ++mt) {
        #pragma unroll
        for (int nt = 0; nt < 6; ++nt) {
            #pragma unroll
            for (int r = 0; r < 4; ++r) {
                int row = mt * 16 + quad * 4 + r;
                float v = acc[mt][nt][r];
                if (zh) v = silu_f(v);
                dstbase[((size_t)b * LSEQ + l0 + row) * DIN + cb + nt * 16 + m16]
                    = f2b(v);
            }
        }
    }
}

// ---------------------------------------------------------------------------
// kB: causal conv(4)+silu -> xc, then x_proj (K=192, chunked register slices).
// LDS 59 KB. grid (64,8), block 256.
// ---------------------------------------------------------------------------
__global__ __launch_bounds__(256) void kB_conv_xproj(
    const u16* __restrict__ xm,
    const float* __restrict__ cvw,  // (192,4)
    const float* __restrict__ cvb,  // (192)
    const float* __restrict__ xpw,  // (38,192)
    u16* __restrict__ xc,           // (BL,192) bf16
    float* __restrict__ dtb,        // (BL,6)
    float* __restrict__ bcb)        // (BL,32)
{
    __shared__ u32 tile[67 * 97];
    __shared__ float wxp[38 * 192];
    __shared__ float cwl[960];
    const int b = blockIdx.y, l0 = blockIdx.x * 64, tid = threadIdx.x;
    const int wv = __builtin_amdgcn_readfirstlane(tid >> 6);
    const int lane = tid & 63;

    for (int i = tid; i < 67 * 96; i += 256) {
        int r = i / 96, d = i % 96, l = l0 - 3 + r;
        tile[r * 97 + d] =
            (l >= 0) ? ((const u32*)xm)[((size_t)b * LSEQ + l) * 96 + d] : 0u;
    }
    for (int i = tid; i < 38 * 192; i += 256) wxp[i] = xpw[i];
    for (int i = tid; i < 960; i += 256) cwl[i] = (i < 768) ? cvw[i] : cvb[i - 768];
    __syncthreads();

    u32 pk[24];
    #pragma unroll
    for (int p = 0; p < 24; ++p) {
        int dd = wv * 24 + p, ch = dd * 2;
        float a0 = cwl[768 + ch], a1 = cwl[768 + ch + 1];
        #pragma unroll
        for (int k = 0; k < 4; ++k) {
            u32 w2 = tile[(lane + k) * 97 + dd];
            a0 = fmaf(cwl[ch * 4 + k],     b2f((u16)(w2 & 0xffff)), a0);
            a1 = fmaf(cwl[ch * 4 + 4 + k], b2f((u16)(w2 >> 16)),    a1);
        }
        pk[p] = (u32)f2b(silu_f(a0)) | ((u32)f2b(silu_f(a1)) << 16);
    }
    __syncthreads();
    #pragma unroll
    for (int p = 0; p < 24; ++p) tile[lane * 97 + wv * 24 + p] = pk[p];
    __syncthreads();

    u32* gxc = (u32*)(xc + ((size_t)b * LSEQ + l0) * DIN);
    for (int i = tid; i < 6144; i += 256) gxc[i] = tile[(i / 96) * 97 + i % 96];

    float acc0[10], acc1[10];
    #pragma unroll
    for (int t = 0; t < 10; ++t) { acc0[t] = 0.0f; acc1[t] = 0.0f; }
    for (int ch = 0; ch < 4; ++ch) {
        u32 vv[24];
        #pragma unroll
        for (int p = 0; p < 24; ++p) vv[p] = tile[lane * 97 + ch * 24 + p];
        #pragma unroll
        for (int t = 0; t < 10; ++t) {
            int c = wv + 4 * t;
            if (c < 38) {
                const float* w = &wxp[c * 192 + ch * 48];
                #pragma unroll
                for (int p = 0; p < 24; ++p) {
                    float2 wp = *(const float2*)(w + 2 * p);
                    acc0[t] = fmaf(b2f((u16)(vv[p] & 0xffff)), wp.x, acc0[t]);
                    acc1[t] = fmaf(b2f((u16)(vv[p] >> 16)),    wp.y, acc1[t]);
                }
            }
        }
    }
    size_t rowg = (size_t)b * LSEQ + l0 + lane;
    #pragma unroll
    for (int t = 0; t < 10; ++t) {
        int c = wv + 4 * t;
        if (c < 38) {
            float a = acc0[t] + acc1[t];
            if (c < DTR) dtb[rowg * DTR + c] = a;
            else         bcb[rowg * 32 + (c - DTR)] = a;
        }
    }
}

// ---------------------------------------------------------------------------
// k3 (pass A): chunk-local scan with h0=0 -> ph [P(16)|hend(16)].
// ---------------------------------------------------------------------------
__global__ __launch_bounds__(192) void k3_scan_partial(
    const u16* __restrict__ xc,
    const float* __restrict__ dtbuf,
    const float* __restrict__ bcb,
    const float* __restrict__ dpw,
    const float* __restrict__ dpb,
    const float* __restrict__ alog,
    float* __restrict__ ph)
{
    __shared__ float dts[CLEN * 6];
    __shared__ float bcs[CLEN * 32];
    __shared__ u16 xcs[CLEN * 192];
    const int b = blockIdx.y, s = blockIdx.x, e = threadIdx.x;
    const size_t rb = (size_t)b * LSEQ + s * CLEN;
    for (int i = e; i < CLEN * 6; i += 192)  dts[i] = dtbuf[rb * 6 + i];
    for (int i = e; i < CLEN * 32; i += 192) bcs[i] = bcb[rb * 32 + i];
    {
        const u32* src = (const u32*)(xc + rb * DIN);
        u32* dd = (u32*)xcs;
        for (int i = e; i < 6144; i += 192) dd[i] = src[i];
    }
    float wr[6];
    #pragma unroll
    for (int r = 0; r < 6; ++r) wr[r] = dpw[e * 6 + r];
    const float bias = dpb[e];
    float m[DST];
    #pragma unroll
    for (int n = 0; n < DST; ++n) m[n] = -__expf(alog[e * DST + n]);
    float h[DST], P[DST];
    #pragma unroll
    for (int n = 0; n < DST; ++n) { h[n] = 0.0f; P[n] = 1.0f; }
    __syncthreads();
    for (int j = 0; j < CLEN; ++j) {
        float u = b2f(xcs[j * 192 + e]);
        float xdt = bias;
        #pragma unroll
        for (int r = 0; r < 6; ++r) xdt = fmaf(dts[j * 6 + r], wr[r], xdt);
        float delta = softplus_f(xdt);
        float du = delta * u;
        #pragma unroll
        for (int n = 0; n < DST; ++n) {
            float dA = __expf(delta * m[n]);
            h[n] = fmaf(dA, h[n], du * bcs[j * 32 + n]);
            P[n] *= dA;
        }
    }
    float* o = ph + (((size_t)b * NCHUNK + s) * 192 + e) * 32;
    #pragma unroll
    for (int n = 0; n < DST; ++n) { o[n] = P[n]; o[16 + n] = h[n]; }
}

// ---------------------------------------------------------------------------
// k4 (pass B): sequential chunk combine, 4x-batched loads.
// ---------------------------------------------------------------------------
__global__ __launch_bounds__(256) void k4_combine(float* __restrict__ ph)
{
    int g = blockIdx.x * 256 + threadIdx.x;
    int b = g / (192 * DST);
    int rem = g % (192 * DST);
    int e = rem / DST, n = rem % DST;
    float h = 0.0f;
    for (int s = 0; s < NCHUNK; s += 4) {
        size_t ix0 = ((size_t)(b * NCHUNK + s) * 192 + e) * 32;
        float P[4], E[4];
        #pragma unroll
        for (int t = 0; t < 4; ++t) {
            P[t] = ph[ix0 + (size_t)t * 6144 + n];
            E[t] = ph[ix0 + (size_t)t * 6144 + 16 + n];
        }
        #pragma unroll
        for (int t = 0; t < 4; ++t) {
            ph[ix0 + (size_t)t * 6144 + n] = h;
            h = fmaf(P[t], h, E[t]);
        }
    }
}

// ---------------------------------------------------------------------------
// k5 (pass C): full scan with h_init; yraw = y + u*D in-place over xc.
// ---------------------------------------------------------------------------
__global__ __launch_bounds__(192) void k5_scan_final(
    u16* __restrict__ xc,
    const float* __restrict__ dtbuf,
    const float* __restrict__ bcb,
    const float* __restrict__ dpw,
    const float* __restrict__ dpb,
    const float* __restrict__ alog,
    const float* __restrict__ Dp,
    const float* __restrict__ ph)
{
    __shared__ float dts[CLEN * 6];
    __shared__ float bcs[CLEN * 32];
    __shared__ u16 xcs[CLEN * 192];
    const int b = blockIdx.y, s = blockIdx.x, e = threadIdx.x;
    const size_t rb = (size_t)b * LSEQ + s * CLEN;
    for (int i = e; i < CLEN * 6; i += 192)  dts[i] = dtbuf[rb * 6 + i];
    for (int i = e; i < CLEN * 32; i += 192) bcs[i] = bcb[rb * 32 + i];
    {
        const u32* src = (const u32*)(xc + rb * DIN);
        u32* dd = (u32*)xcs;
        for (int i = e; i < 6144; i += 192) dd[i] = src[i];
    }
    float wr[6];
    #pragma unroll
    for (int r = 0; r < 6; ++r) wr[r] = dpw[e * 6 + r];
    const float bias = dpb[e];
    const float De = Dp[e];
    float m[DST];
    #pragma unroll
    for (int n = 0; n < DST; ++n) m[n] = -__expf(alog[e * DST + n]);
    float h[DST];
    const float* hi = ph + (((size_t)b * NCHUNK + s) * 192 + e) * 32;
    #pragma unroll
    for (int n = 0; n < DST; ++n) h[n] = hi[n];
    __syncthreads();
    for (int j = 0; j < CLEN; ++j) {
        float u = b2f(xcs[j * 192 + e]);
        float xdt = bias;
        #pragma unroll
        for (int r = 0; r < 6; ++r) xdt = fmaf(dts[j * 6 + r], wr[r], xdt);
        float delta = softplus_f(xdt);
        float du = delta * u;
        float y = 0.0f;
        #pragma unroll
        for (int n = 0; n < DST; ++n) {
            float dA = __expf(delta * m[n]);
            h[n] = fmaf(dA, h[n], du * bcs[j * 32 + n]);
            y = fmaf(h[n], bcs[j * 32 + 16 + n], y);
        }
        xc[(rb + j) * DIN + e] = f2b(y + u * De);
    }
}

// ---------------------------------------------------------------------------
// k6: gate -> yt LDS -> out_proj (24 reg results, fp32 LDS weights, 2 halves)
// -> ot reuses yt -> LN(96) -> transposed store. LDS 61.5 KB.
// ---------------------------------------------------------------------------
__global__ __launch_bounds__(256) void k6_gate_outproj_ln(
    const u16* __restrict__ yraw,
    const u16* __restrict__ zsb,
    const float* __restrict__ opw,  // (96,192)
    const float* __restrict__ gam,
    const float* __restrict__ bet,
    float* __restrict__ out)        // (8,96,4096)
{
    __shared__ __align__(16) char smem[25600 + 36864 + 512];
    u32* yt = (u32*)smem;                       // [64][100] gated bf16-pairs
    float* wop = (float*)(smem + 25600);        // [48][192]
    float* mu = (float*)(smem + 25600 + 36864); // [64]
    float* rs = mu + 64;
    float* ot = (float*)smem;                   // [64][97] fp32 (reuse)
    const int b = blockIdx.y, l0 = blockIdx.x * 64, tid = threadIdx.x;
    const int wv = __builtin_amdgcn_readfirstlane(tid >> 6);
    const int lane = tid & 63;
    const u32* yr = (const u32*)(yraw + ((size_t)b * LSEQ + l0) * DIN);
    const u32* zr = (const u32*)(zsb + ((size_t)b * LSEQ + l0) * DIN);
    for (int i = tid; i < 6144; i += 256) {
        u32 a = yr[i], z = zr[i];
        float y0 = b2f((u16)(a & 0xffff)) * b2f((u16)(z & 0xffff));
        float y1 = b2f((u16)(a >> 16)) * b2f((u16)(z >> 16));
        yt[(i / 96) * 100 + i % 96] = (u32)f2b(y0) | ((u32)f2b(y1) << 16);
    }
    __syncthreads();
    float rc[24];
    for (int half = 0; half < 2; ++half) {
        const float* wsrc = opw + (size_t)half * 9216;
        for (int i = tid; i < 9216; i += 256) wop[i] = wsrc[i];
        __syncthreads();
        for (int jp = 0; jp < 6; ++jp) {
            int lc = wv * 12 + jp * 2;
            const float4* w0 = (const float4*)&wop[lc * 192];
            const float4* w1 = (const float4*)&wop[(lc + 1) * 192];
            float a0 = 0.0f, a1 = 0.0f;
            #pragma unroll
            for (int k4 = 0; k4 < 24; ++k4) {
                uint4 q = *(const uint4*)&yt[lane * 100 + k4 * 4];
                float y0 = b2f((u16)(q.x & 0xffff)), y1 = b2f((u16)(q.x >> 16));
                float y2 = b2f((u16)(q.y & 0xffff)), y3 = b2f((u16)(q.y >> 16));
                float y4 = b2f((u16)(q.z & 0xffff)), y5 = b2f((u16)(q.z >> 16));
                float y6 = b2f((u16)(q.w & 0xffff)), y7 = b2f((u16)(q.w >> 16));
                float4 p = w0[k4 * 2], r = w0[k4 * 2 + 1];
                a0 = fmaf(y0,p.x,fmaf(y1,p.y,fmaf(y2,p.z,fmaf(y3,p.w,a0))));
                a0 = fmaf(y4,r.x,fmaf(y5,r.y,fmaf(y6,r.z,fmaf(y7,r.w,a0))));
                p = w1[k4 * 2]; r = w1[k4 * 2 + 1];
                a1 = fmaf(y0,p.x,fmaf(y1,p.y,fmaf(y2,p.z,fmaf(y3,p.w,a1))));
                a1 = fmaf(y4,r.x,fmaf(y5,r.y,fmaf(y6,r.z,fmaf(y7,r.w,a1))));
            }
            rc[half * 12 + jp * 2]     = a0;
            rc[half * 12 + jp * 2 + 1] = a1;
        }
        __syncthreads();
    }
    #pragma unroll
    for (int t = 0; t < 24; ++t) {
        int c = (t / 12) * 48 + wv * 12 + (t % 12);
        ot[lane * 97 + c] = rc[t];
    }
    __syncthreads();
    if (tid < 64) {
        float s = 0.0f;
        for (int c = 0; c < 96; ++c) s += ot[tid * 97 + c];
        float mean = s * (1.0f / 96.0f);
        float v = 0.0f;
        for (int c = 0; c < 96; ++c) {
            float d = ot[tid * 97 + c] - mean;
            v = fmaf(d, d, v);
        }
        mu[tid] = mean;
        rs[tid] = rsqrtf(v * (1.0f / 96.0f) + 1e-5f);
    }
    __syncthreads();
    for (int idx = tid; idx < 6144; idx += 256) {
        int c = idx / 64, lr = idx % 64;
        float val = (ot[lr * 97 + c] - mu[lr]) * rs[lr] * gam[c] + bet[c];
        out[((size_t)b * CDIM + c) * LSEQ + l0 + lr] = val;
    }
}

extern "C" void kernel_launch(void* const* d_in, const int* in_sizes, int n_in,
                              void* d_out, int out_size, void* d_ws, size_t ws_size,
                              hipStream_t stream) {
    const float* x    = (const float*)d_in[0];
    const float* ipw  = (const float*)d_in[1];
    const float* cvw  = (const float*)d_in[2];
    const float* cvb  = (const float*)d_in[3];
    const float* xpw  = (const float*)d_in[4];
    const float* dpw  = (const float*)d_in[5];
    const float* dpb  = (const float*)d_in[6];
    const float* alog = (const float*)d_in[7];
    const float* Dp   = (const float*)d_in[8];
    const float* opw  = (const float*)d_in[9];
    const float* gam  = (const float*)d_in[10];
    const float* bet  = (const float*)d_in[11];
    float* out = (float*)d_out;

    // Workspace 42.8 MB. xm dead after kB; ph aliases it (same 12.6 MB).
    u16* xm    = (u16*)d_ws;
    u16* zsb   = xm + (size_t)BL * DIN;
    u16* xc    = zsb + (size_t)BL * DIN;
    float* dtb = (float*)(xc + (size_t)BL * DIN);
    float* bcb = dtb + (size_t)BL * DTR;
    float* ph  = (float*)xm;

    kA_inproj<<<dim3(LSEQ / 64, BATCH), 256, 0, stream>>>(x, ipw, xm, zsb);
    kB_conv_xproj<<<dim3(LSEQ / 64, BATCH), 256, 0, stream>>>(
        xm, cvw, cvb, xpw, xc, dtb, bcb);
    k3_scan_partial<<<dim3(NCHUNK, BATCH), 192, 0, stream>>>(
        xc, dtb, bcb, dpw, dpb, alog, ph);
    k4_combine<<<dim3(BATCH * 192 * DST / 256), 256, 0, stream>>>(ph);
    k5_scan_final<<<dim3(NCHUNK, BATCH), 192, 0, stream>>>(
        xc, dtb, bcb, dpw, dpb, alog, Dp, ph);
    k6_gate_outproj_ln<<<dim3(LSEQ / 64, BATCH), 256, 0, stream>>>(
        xc, zsb, opw, gam, bet, out);
}